// Round 1
// baseline (599.191 us; speedup 1.0000x reference)
//
#include <hip/hip_runtime.h>
#include <hip/hip_bf16.h>

// ---------------- types & helpers ----------------
typedef __attribute__((ext_vector_type(8))) short short8;   // 8 bf16 (4 VGPR)
typedef __attribute__((ext_vector_type(4))) float f32x4;    // MFMA C/D frag

#define GLOB_AS __attribute__((address_space(1)))
#define LDS_AS  __attribute__((address_space(3)))

__device__ __forceinline__ void async16(void* lds, const void* g) {
  __builtin_amdgcn_global_load_lds((const GLOB_AS unsigned int*)g,
                                   (LDS_AS unsigned int*)lds, 16, 0, 0);
}

__device__ __forceinline__ unsigned short f2bf(float f) {
  unsigned u = __float_as_uint(f);
  unsigned r = u + 0x7FFFu + ((u >> 16) & 1u);   // RNE
  return (unsigned short)(r >> 16);
}

// dims
#define BATCH 4
#define SEQ   2048
#define DMODEL 1024
#define NHEAD 4
#define HD    256

// ---------------- cast x -> bf16 ----------------
__global__ __launch_bounds__(256) void cast_bf16_kernel(
    const float* __restrict__ in, unsigned short* __restrict__ out) {
  int i = blockIdx.x * 256 + threadIdx.x;   // handles 4 elements
  float4 v = ((const float4*)in)[i];
  uint2 o;
  o.x = (unsigned)f2bf(v.x) | ((unsigned)f2bf(v.y) << 16);
  o.y = (unsigned)f2bf(v.z) | ((unsigned)f2bf(v.w) << 16);
  ((uint2*)out)[i] = o;
}

// ---------------- transpose + cast weights: out[c][r] = bf16(in[r][c]) ----------------
__global__ __launch_bounds__(256) void transpose_cast_kernel(
    const float* __restrict__ in, unsigned short* __restrict__ out, int R, int C) {
  __shared__ float tile[32][33];
  int c0 = blockIdx.x * 32, r0 = blockIdx.y * 32;
  int tx = threadIdx.x, ty = threadIdx.y;  // (32, 8)
#pragma unroll
  for (int i = 0; i < 4; ++i)
    tile[ty + 8 * i][tx] = in[(size_t)(r0 + ty + 8 * i) * C + c0 + tx];
  __syncthreads();
#pragma unroll
  for (int i = 0; i < 4; ++i)
    out[(size_t)(c0 + ty + 8 * i) * R + r0 + tx] = f2bf(tile[tx][ty + 8 * i]);
}

// ---------------- QKV GEMM: C[8192,3072] = xb * wqkvT^T + b ----------------
// 128x128 tile, BK=32, 4 waves (2x2), each wave 64x64 = 4x4 MFMA frags.
__global__ __launch_bounds__(256) void gemm_qkv_kernel(
    const unsigned short* __restrict__ A,    // xb   [8192][1024]
    const unsigned short* __restrict__ Bt,   // wqkvT[3072][1024]
    const float* __restrict__ bias,          // [3072]
    unsigned short* __restrict__ qb,         // [16][2048][256]
    unsigned short* __restrict__ kb,         // [16][2048][256]
    unsigned short* __restrict__ vt) {       // [16][256][2048]
  __shared__ __align__(16) unsigned short sA[128 * 32];
  __shared__ __align__(16) unsigned short sB[128 * 32];
  const int t = threadIdx.x;
  const int l = t & 63, w = t >> 6;
  const int g = l >> 4, lr = l & 15;
  const int wr = w >> 1, wc = w & 1;
  const int row0 = blockIdx.y * 128;
  const int col0 = blockIdx.x * 128;

  f32x4 acc[4][4] = {};
  for (int kt = 0; kt < 1024; kt += 32) {
    __syncthreads();
#pragma unroll
    for (int i = 0; i < 2; ++i) {
      int e = i * 256 + t;
      async16(&sA[e * 8], A + (size_t)(row0 + (e >> 2)) * 1024 + kt + (e & 3) * 8);
      async16(&sB[e * 8], Bt + (size_t)(col0 + (e >> 2)) * 1024 + kt + (e & 3) * 8);
    }
    __syncthreads();
    short8 af[4], bf[4];
#pragma unroll
    for (int m = 0; m < 4; ++m)
      af[m] = *(const short8*)&sA[(wr * 64 + m * 16 + lr) * 32 + g * 8];
#pragma unroll
    for (int n = 0; n < 4; ++n)
      bf[n] = *(const short8*)&sB[(wc * 64 + n * 16 + lr) * 32 + g * 8];
#pragma unroll
    for (int m = 0; m < 4; ++m)
#pragma unroll
      for (int n = 0; n < 4; ++n)
        acc[m][n] = __builtin_amdgcn_mfma_f32_16x16x32_bf16(af[m], bf[n], acc[m][n], 0, 0, 0);
  }

  // epilogue: C layout col=lane&15, row=(lane>>4)*4+reg
#pragma unroll
  for (int m = 0; m < 4; ++m) {
    int rowb = row0 + wr * 64 + m * 16 + g * 4;  // + rr
    int b = rowb >> 11;
    int nb = rowb & 2047;
#pragma unroll
    for (int nn = 0; nn < 4; ++nn) {
      int col = col0 + wc * 64 + nn * 16 + lr;
      float bv = bias[col];
      int sec = col >> 10, c1 = col & 1023;
      int h = c1 >> 8, d = c1 & 255;
      if (sec == 2) {  // V -> transposed [bh][d][n], pack 4 consecutive n
        unsigned short p0 = f2bf(acc[m][nn][0] + bv);
        unsigned short p1 = f2bf(acc[m][nn][1] + bv);
        unsigned short p2 = f2bf(acc[m][nn][2] + bv);
        unsigned short p3 = f2bf(acc[m][nn][3] + bv);
        uint2 pk;
        pk.x = (unsigned)p0 | ((unsigned)p1 << 16);
        pk.y = (unsigned)p2 | ((unsigned)p3 << 16);
        size_t idx = ((size_t)((b * NHEAD + h) * HD + d)) * SEQ + nb;
        *(uint2*)&vt[idx] = pk;
      } else {
        unsigned short* dst = (sec == 0) ? qb : kb;
#pragma unroll
        for (int rr = 0; rr < 4; ++rr) {
          size_t idx = ((size_t)((b * NHEAD + h) * SEQ + nb + rr)) * HD + d;
          dst[idx] = f2bf(acc[m][nn][rr] + bv);
        }
      }
    }
  }
}

// ---------------- attention: per-wave 16 q rows, swapped orientation ----------------
// S^T[kp][q] = sum_d K[kp][d] Q[q][d]   (A=K frag, B=Q frag)
// acc^T[d][q] += sum_kp V^T[d][kp] P^T[kp][q]  (A=V^T frag, B=P frag from LDS)
__global__ __launch_bounds__(256) void attn_kernel(
    const unsigned short* __restrict__ qb,
    const unsigned short* __restrict__ kb,
    const unsigned short* __restrict__ vt,
    unsigned short* __restrict__ ao) {       // [8192][1024] bf16
  __shared__ __align__(16) unsigned short P[4][16 * 40];  // per-wave, padded stride 40
  const int t = threadIdx.x, l = t & 63, w = t >> 6;
  const int g = l >> 4, lq = l & 15;
  const int bh = blockIdx.y;                 // b*NHEAD + h
  const int b = bh >> 2, h = bh & 3;
  const int q = blockIdx.x * 64 + w * 16 + lq;  // q row in [0, SEQ)
  const unsigned short* Qp = qb + (size_t)bh * SEQ * HD;
  const unsigned short* Kp = kb + (size_t)bh * SEQ * HD;
  const unsigned short* Vp = vt + (size_t)bh * HD * SEQ;

  short8 qf[8];
#pragma unroll
  for (int dc = 0; dc < 8; ++dc)
    qf[dc] = *(const short8*)&Qp[(size_t)q * HD + dc * 32 + g * 8];

  f32x4 acc[16] = {};
  float mrun = -__builtin_inff();
  float lsum = 0.f;
  const float scale = 0.0625f;  // 1/sqrt(256)

  for (int kp0 = 0; kp0 < SEQ; kp0 += 32) {
    __syncthreads();  // keep the block's 4 waves time-aligned for K/V cache reuse
    f32x4 s0 = {}, s1 = {};
#pragma unroll
    for (int dc = 0; dc < 8; ++dc) {
      short8 k0 = *(const short8*)&Kp[(size_t)(kp0 + lq) * HD + dc * 32 + g * 8];
      short8 k1 = *(const short8*)&Kp[(size_t)(kp0 + 16 + lq) * HD + dc * 32 + g * 8];
      s0 = __builtin_amdgcn_mfma_f32_16x16x32_bf16(k0, qf[dc], s0, 0, 0, 0);
      s1 = __builtin_amdgcn_mfma_f32_16x16x32_bf16(k1, qf[dc], s1, 0, 0, 0);
    }
    float sv[8];
#pragma unroll
    for (int i = 0; i < 4; ++i) { sv[i] = s0[i] * scale; sv[4 + i] = s1[i] * scale; }
    float cmax = sv[0];
#pragma unroll
    for (int i = 1; i < 8; ++i) cmax = fmaxf(cmax, sv[i]);
    cmax = fmaxf(cmax, __shfl_xor(cmax, 16));
    cmax = fmaxf(cmax, __shfl_xor(cmax, 32));

    // defer-max: only rescale when the running max moved by > 8
    if (!__all(cmax <= mrun + 8.0f)) {
      float mnew = fmaxf(mrun, cmax);
      float alpha = __expf(mrun - mnew);
      lsum *= alpha;
#pragma unroll
      for (int dt = 0; dt < 16; ++dt) {
#pragma unroll
        for (int rr = 0; rr < 4; ++rr) acc[dt][rr] *= alpha;
      }
      mrun = mnew;
    }

    float ps = 0.f;
    unsigned short pb[8];
#pragma unroll
    for (int i = 0; i < 8; ++i) {
      float p = __expf(sv[i] - mrun);
      ps += p;
      pb[i] = f2bf(p);
    }
    ps += __shfl_xor(ps, 16);
    ps += __shfl_xor(ps, 32);
    lsum += ps;

    // write P^T to per-wave LDS as P[q][kp], kp = frag*16 + g*4 + rr
    unsigned* pw0 = (unsigned*)&P[w][lq * 40 + g * 4];
    pw0[0] = (unsigned)pb[0] | ((unsigned)pb[1] << 16);
    pw0[1] = (unsigned)pb[2] | ((unsigned)pb[3] << 16);
    unsigned* pw1 = (unsigned*)&P[w][lq * 40 + 16 + g * 4];
    pw1[0] = (unsigned)pb[4] | ((unsigned)pb[5] << 16);
    pw1[1] = (unsigned)pb[6] | ((unsigned)pb[7] << 16);

    // B-frag: P^T[kp = g*8+j][q = lq]
    short8 pf = *(const short8*)&P[w][lq * 40 + g * 8];
#pragma unroll
    for (int dt = 0; dt < 16; ++dt) {
      short8 vf = *(const short8*)&Vp[(size_t)(dt * 16 + lq) * SEQ + kp0 + g * 8];
      acc[dt] = __builtin_amdgcn_mfma_f32_16x16x32_bf16(vf, pf, acc[dt], 0, 0, 0);
    }
  }

  float inv = 1.0f / lsum;
  size_t obase = ((size_t)(b * SEQ + q)) * DMODEL + h * HD;
#pragma unroll
  for (int dt = 0; dt < 16; ++dt) {
    unsigned short o0 = f2bf(acc[dt][0] * inv);
    unsigned short o1 = f2bf(acc[dt][1] * inv);
    unsigned short o2 = f2bf(acc[dt][2] * inv);
    unsigned short o3 = f2bf(acc[dt][3] * inv);
    uint2 pk;
    pk.x = (unsigned)o0 | ((unsigned)o1 << 16);
    pk.y = (unsigned)o2 | ((unsigned)o3 << 16);
    *(uint2*)&ao[obase + dt * 16 + g * 4] = pk;
  }
}

// ---------------- out projection + bias + residual -> y (fp32) ----------------
__global__ __launch_bounds__(256) void gemm_out_kernel(
    const unsigned short* __restrict__ A,    // attn_out [8192][1024]
    const unsigned short* __restrict__ Bt,   // woutT    [1024][1024]
    const float* __restrict__ bias,          // [1024]
    const float* __restrict__ x,             // [8192][1024] fp32
    float* __restrict__ y) {                 // [8192][1024] fp32
  __shared__ __align__(16) unsigned short sA[128 * 32];
  __shared__ __align__(16) unsigned short sB[128 * 32];
  const int t = threadIdx.x;
  const int l = t & 63, w = t >> 6;
  const int g = l >> 4, lr = l & 15;
  const int wr = w >> 1, wc = w & 1;
  const int row0 = blockIdx.y * 128;
  const int col0 = blockIdx.x * 128;

  f32x4 acc[4][4] = {};
  for (int kt = 0; kt < 1024; kt += 32) {
    __syncthreads();
#pragma unroll
    for (int i = 0; i < 2; ++i) {
      int e = i * 256 + t;
      async16(&sA[e * 8], A + (size_t)(row0 + (e >> 2)) * 1024 + kt + (e & 3) * 8);
      async16(&sB[e * 8], Bt + (size_t)(col0 + (e >> 2)) * 1024 + kt + (e & 3) * 8);
    }
    __syncthreads();
    short8 af[4], bf[4];
#pragma unroll
    for (int m = 0; m < 4; ++m)
      af[m] = *(const short8*)&sA[(wr * 64 + m * 16 + lr) * 32 + g * 8];
#pragma unroll
    for (int n = 0; n < 4; ++n)
      bf[n] = *(const short8*)&sB[(wc * 64 + n * 16 + lr) * 32 + g * 8];
#pragma unroll
    for (int m = 0; m < 4; ++m)
#pragma unroll
      for (int n = 0; n < 4; ++n)
        acc[m][n] = __builtin_amdgcn_mfma_f32_16x16x32_bf16(af[m], bf[n], acc[m][n], 0, 0, 0);
  }

#pragma unroll
  for (int m = 0; m < 4; ++m) {
    int rowb = row0 + wr * 64 + m * 16 + g * 4;
#pragma unroll
    for (int nn = 0; nn < 4; ++nn) {
      int col = col0 + wc * 64 + nn * 16 + lr;
      float bv = bias[col];
#pragma unroll
      for (int rr = 0; rr < 4; ++rr) {
        size_t idx = (size_t)(rowb + rr) * 1024 + col;
        y[idx] = acc[m][nn][rr] + bv + x[idx];
      }
    }
  }
}

// ---------------- LayerNorm over last dim (1024) ----------------
__global__ __launch_bounds__(256) void ln_kernel(
    const float* __restrict__ y, const float* __restrict__ gamma,
    const float* __restrict__ beta, float* __restrict__ out) {
  int row = blockIdx.x, t = threadIdx.x;
  float4 v = ((const float4*)(y + (size_t)row * 1024))[t];
  float s = v.x + v.y + v.z + v.w;
  float qs = v.x * v.x + v.y * v.y + v.z * v.z + v.w * v.w;
#pragma unroll
  for (int off = 1; off < 64; off <<= 1) {
    s += __shfl_xor(s, off);
    qs += __shfl_xor(qs, off);
  }
  __shared__ float ss[4], qq[4];
  if ((t & 63) == 0) { ss[t >> 6] = s; qq[t >> 6] = qs; }
  __syncthreads();
  s = ss[0] + ss[1] + ss[2] + ss[3];
  qs = qq[0] + qq[1] + qq[2] + qq[3];
  float mean = s * (1.0f / 1024.0f);
  float var = qs * (1.0f / 1024.0f) - mean * mean;
  float rstd = rsqrtf(var + 1e-5f);
  float4 gm = ((const float4*)gamma)[t];
  float4 bt = ((const float4*)beta)[t];
  float4 o;
  o.x = (v.x - mean) * rstd * gm.x + bt.x;
  o.y = (v.y - mean) * rstd * gm.y + bt.y;
  o.z = (v.z - mean) * rstd * gm.z + bt.z;
  o.w = (v.w - mean) * rstd * gm.w + bt.w;
  ((float4*)(out + (size_t)row * 1024))[t] = o;
}

// ---------------- launch ----------------
extern "C" void kernel_launch(void* const* d_in, const int* in_sizes, int n_in,
                              void* d_out, int out_size, void* d_ws, size_t ws_size,
                              hipStream_t stream) {
  const float* x      = (const float*)d_in[0];
  const float* w_qkv  = (const float*)d_in[1];
  const float* b_qkv  = (const float*)d_in[2];
  const float* w_out  = (const float*)d_in[3];
  const float* b_out  = (const float*)d_in[4];
  const float* gamma  = (const float*)d_in[5];
  const float* beta   = (const float*)d_in[6];
  float* out = (float*)d_out;

  char* ws = (char*)d_ws;
  unsigned short* xb    = (unsigned short*)(ws);                 // 16 MB
  unsigned short* wqkvT = (unsigned short*)(ws + (16u << 20));   //  6 MB
  unsigned short* woutT = (unsigned short*)(ws + (22u << 20));   //  2 MB
  unsigned short* qb    = (unsigned short*)(ws + (24u << 20));   // 16 MB
  unsigned short* kb    = (unsigned short*)(ws + (40u << 20));   // 16 MB
  unsigned short* vt    = (unsigned short*)(ws + (56u << 20));   // 16 MB
  unsigned short* ao    = (unsigned short*)(ws + (72u << 20));   // 16 MB
  float* y              = (float*)(ws + (88u << 20));            // 32 MB

  cast_bf16_kernel<<<(BATCH * SEQ * DMODEL) / (256 * 4), 256, 0, stream>>>(x, xb);
  transpose_cast_kernel<<<dim3(96, 32), dim3(32, 8), 0, stream>>>(w_qkv, wqkvT, 1024, 3072);
  transpose_cast_kernel<<<dim3(32, 32), dim3(32, 8), 0, stream>>>(w_out, woutT, 1024, 1024);
  gemm_qkv_kernel<<<dim3(24, 64), 256, 0, stream>>>(xb, wqkvT, b_qkv, qb, kb, vt);
  attn_kernel<<<dim3(32, 16), 256, 0, stream>>>(qb, kb, vt, ao);
  gemm_out_kernel<<<dim3(8, 64), 256, 0, stream>>>(ao, woutT, b_out, x, y);
  ln_kernel<<<BATCH * SEQ, 256, 0, stream>>>(y, gamma, beta, out);
}

// Round 2
// 412.713 us; speedup vs baseline: 1.4518x; 1.4518x over previous
//
#include <hip/hip_runtime.h>
#include <hip/hip_bf16.h>

// ---------------- types & helpers ----------------
typedef __attribute__((ext_vector_type(8))) short short8;   // 8 bf16 (4 VGPR)
typedef __attribute__((ext_vector_type(4))) float f32x4;    // MFMA C/D frag

#define GLOB_AS __attribute__((address_space(1)))
#define LDS_AS  __attribute__((address_space(3)))

__device__ __forceinline__ void async16(void* lds, const void* g) {
  __builtin_amdgcn_global_load_lds((const GLOB_AS unsigned int*)g,
                                   (LDS_AS unsigned int*)lds, 16, 0, 0);
}

__device__ __forceinline__ unsigned short f2bf(float f) {
  unsigned u = __float_as_uint(f);
  unsigned r = u + 0x7FFFu + ((u >> 16) & 1u);   // RNE
  return (unsigned short)(r >> 16);
}

// dims
#define BATCH 4
#define SEQ   2048
#define DMODEL 1024
#define NHEAD 4
#define HD    256

// ---------------- cast x -> bf16 ----------------
__global__ __launch_bounds__(256) void cast_bf16_kernel(
    const float* __restrict__ in, unsigned short* __restrict__ out) {
  int i = blockIdx.x * 256 + threadIdx.x;   // handles 4 elements
  float4 v = ((const float4*)in)[i];
  uint2 o;
  o.x = (unsigned)f2bf(v.x) | ((unsigned)f2bf(v.y) << 16);
  o.y = (unsigned)f2bf(v.z) | ((unsigned)f2bf(v.w) << 16);
  ((uint2*)out)[i] = o;
}

// ---------------- transpose + cast weights: out[c][r] = bf16(in[r][c]) ----------------
__global__ __launch_bounds__(256) void transpose_cast_kernel(
    const float* __restrict__ in, unsigned short* __restrict__ out, int R, int C) {
  __shared__ float tile[32][33];
  int c0 = blockIdx.x * 32, r0 = blockIdx.y * 32;
  int tx = threadIdx.x, ty = threadIdx.y;  // (32, 8)
#pragma unroll
  for (int i = 0; i < 4; ++i)
    tile[ty + 8 * i][tx] = in[(size_t)(r0 + ty + 8 * i) * C + c0 + tx];
  __syncthreads();
#pragma unroll
  for (int i = 0; i < 4; ++i)
    out[(size_t)(c0 + ty + 8 * i) * R + r0 + tx] = f2bf(tile[tx][ty + 8 * i]);
}

// ---------------- QKV GEMM: C[8192,3072] = xb * wqkvT^T + b ----------------
__global__ __launch_bounds__(256) void gemm_qkv_kernel(
    const unsigned short* __restrict__ A,    // xb   [8192][1024]
    const unsigned short* __restrict__ Bt,   // wqkvT[3072][1024]
    const float* __restrict__ bias,          // [3072]
    unsigned short* __restrict__ qb,         // [16][2048][256]
    unsigned short* __restrict__ kb,         // [16][2048][256]
    unsigned short* __restrict__ vt) {       // [16][256][2048]
  __shared__ __align__(16) unsigned short sA[128 * 32];
  __shared__ __align__(16) unsigned short sB[128 * 32];
  const int t = threadIdx.x;
  const int l = t & 63, w = t >> 6;
  const int g = l >> 4, lr = l & 15;
  const int wr = w >> 1, wc = w & 1;
  const int row0 = blockIdx.y * 128;
  const int col0 = blockIdx.x * 128;

  f32x4 acc[4][4] = {};
  for (int kt = 0; kt < 1024; kt += 32) {
    __syncthreads();
#pragma unroll
    for (int i = 0; i < 2; ++i) {
      int e = i * 256 + t;
      async16(&sA[e * 8], A + (size_t)(row0 + (e >> 2)) * 1024 + kt + (e & 3) * 8);
      async16(&sB[e * 8], Bt + (size_t)(col0 + (e >> 2)) * 1024 + kt + (e & 3) * 8);
    }
    __syncthreads();
    short8 af[4], bf[4];
#pragma unroll
    for (int m = 0; m < 4; ++m)
      af[m] = *(const short8*)&sA[(wr * 64 + m * 16 + lr) * 32 + g * 8];
#pragma unroll
    for (int n = 0; n < 4; ++n)
      bf[n] = *(const short8*)&sB[(wc * 64 + n * 16 + lr) * 32 + g * 8];
#pragma unroll
    for (int m = 0; m < 4; ++m)
#pragma unroll
      for (int n = 0; n < 4; ++n)
        acc[m][n] = __builtin_amdgcn_mfma_f32_16x16x32_bf16(af[m], bf[n], acc[m][n], 0, 0, 0);
  }

  // epilogue: C layout col=lane&15, row=(lane>>4)*4+reg
#pragma unroll
  for (int m = 0; m < 4; ++m) {
    int rowb = row0 + wr * 64 + m * 16 + g * 4;  // + rr
    int b = rowb >> 11;
    int nb = rowb & 2047;
#pragma unroll
    for (int nn = 0; nn < 4; ++nn) {
      int col = col0 + wc * 64 + nn * 16 + lr;
      float bv = bias[col];
      int sec = col >> 10, c1 = col & 1023;
      int h = c1 >> 8, d = c1 & 255;
      if (sec == 2) {  // V -> transposed [bh][d][n], pack 4 consecutive n
        unsigned short p0 = f2bf(acc[m][nn][0] + bv);
        unsigned short p1 = f2bf(acc[m][nn][1] + bv);
        unsigned short p2 = f2bf(acc[m][nn][2] + bv);
        unsigned short p3 = f2bf(acc[m][nn][3] + bv);
        uint2 pk;
        pk.x = (unsigned)p0 | ((unsigned)p1 << 16);
        pk.y = (unsigned)p2 | ((unsigned)p3 << 16);
        size_t idx = ((size_t)((b * NHEAD + h) * HD + d)) * SEQ + nb;
        *(uint2*)&vt[idx] = pk;
      } else {
        unsigned short* dst = (sec == 0) ? qb : kb;
#pragma unroll
        for (int rr = 0; rr < 4; ++rr) {
          size_t idx = ((size_t)((b * NHEAD + h) * SEQ + nb + rr)) * HD + d;
          dst[idx] = f2bf(acc[m][nn][rr] + bv);
        }
      }
    }
  }
}

// ---------------- attention ----------------
// Per-wave 16 q rows, swapped orientation:
//   S^T[kp][q]   = sum_d K[kp][d] Q[q][d]        (A = K frag from LDS, B = Q frag)
//   acc^T[d][q] += sum_kp V^T[d][kp] P^T[kp][q]  (A = V^T frag from global, B = P frag)
// K chunk [32][256] double-buffered in LDS via global_load_lds, XOR-swizzled
// (byte ^= (row&7)<<4) through pre-swizzled per-lane SOURCE addresses.
// XCD swizzle: blocks of the same head pinned to one XCD for L2 residency.
__global__ __launch_bounds__(256, 2) void attn_kernel(
    const unsigned short* __restrict__ qb,
    const unsigned short* __restrict__ kb,
    const unsigned short* __restrict__ vt,
    unsigned short* __restrict__ ao) {       // [8192][1024] bf16
  __shared__ __align__(16) unsigned short sK[2][32 * 256];   // 16 KB per buffer
  __shared__ __align__(16) unsigned short P[4][16 * 40];     // per-wave, stride 40
  const int t = threadIdx.x, l = t & 63, w = t >> 6;
  const int g = l >> 4, lq = l & 15;
  // XCD-aware decode: bid%8 == XCD; XCD x owns heads {2x, 2x+1}
  const int bid = blockIdx.x;
  const int bh = (bid & 7) * 2 + ((bid >> 3) & 1);
  const int qblk = bid >> 4;
  const int b = bh >> 2, h = bh & 3;
  const int q = qblk * 64 + w * 16 + lq;
  const unsigned short* Qp = qb + (size_t)bh * SEQ * HD;
  const char* Kg = (const char*)(kb + (size_t)bh * SEQ * HD);
  const unsigned short* Vp = vt + (size_t)bh * HD * SEQ;

  short8 qf[8];
#pragma unroll
  for (int dc = 0; dc < 8; ++dc)
    qf[dc] = *(const short8*)&Qp[(size_t)q * HD + dc * 32 + g * 8];

  // stage K chunk [kp0..kp0+32) into sK[buf], linear LDS dest + inverse-swizzled src
  auto stage = [&](int buf, int kp0) {
#pragma unroll
    for (int i = 0; i < 4; ++i) {
      int s = w * 256 + i * 64 + l;            // 16B slot index, 0..1023
      int row = s >> 5;                         // 0..31
      int colb = (s & 31) * 16;                 // byte col in row
      int src = (kp0 + row) * 512 + (colb ^ ((row & 7) << 4));
      async16((char*)sK[buf] + s * 16, Kg + src);
    }
  };

  stage(0, 0);
  __syncthreads();

  f32x4 acc[16] = {};
  float mrun = -__builtin_inff();
  float lsum = 0.f;
  const float scale = 0.0625f;  // 1/sqrt(256)

  for (int it = 0; it < 64; ++it) {
    const int kp0 = it * 32;
    const int cur = it & 1;
    if (it < 63) stage(cur ^ 1, kp0 + 32);   // prefetch next chunk (async)

    // early V issue: consumed only after softmax, ~400cy later
    short8 vf[16];
#pragma unroll
    for (int dt = 0; dt < 16; ++dt)
      vf[dt] = *(const short8*)&Vp[(size_t)(dt * 16 + lq) * SEQ + kp0 + g * 8];

    // QK^T from swizzled LDS K
    f32x4 s0 = {}, s1 = {};
    __builtin_amdgcn_s_setprio(1);
#pragma unroll
    for (int dc = 0; dc < 8; ++dc) {
      int c = dc * 64 + g * 16;
      short8 k0 = *(const short8*)((const char*)sK[cur] +
                    (lq * 512 + (c ^ ((lq & 7) << 4))));
      short8 k1 = *(const short8*)((const char*)sK[cur] +
                    ((lq + 16) * 512 + (c ^ ((lq & 7) << 4))));
      s0 = __builtin_amdgcn_mfma_f32_16x16x32_bf16(k0, qf[dc], s0, 0, 0, 0);
      s1 = __builtin_amdgcn_mfma_f32_16x16x32_bf16(k1, qf[dc], s1, 0, 0, 0);
    }
    __builtin_amdgcn_s_setprio(0);

    float sv[8];
#pragma unroll
    for (int i = 0; i < 4; ++i) { sv[i] = s0[i] * scale; sv[4 + i] = s1[i] * scale; }
    float cmax = sv[0];
#pragma unroll
    for (int i = 1; i < 8; ++i) cmax = fmaxf(cmax, sv[i]);
    cmax = fmaxf(cmax, __shfl_xor(cmax, 16));
    cmax = fmaxf(cmax, __shfl_xor(cmax, 32));

    // defer-max: only rescale when running max moved by > 8
    if (!__all(cmax <= mrun + 8.0f)) {
      float mnew = fmaxf(mrun, cmax);
      float alpha = __expf(mrun - mnew);
      lsum *= alpha;
#pragma unroll
      for (int dt = 0; dt < 16; ++dt) {
#pragma unroll
        for (int rr = 0; rr < 4; ++rr) acc[dt][rr] *= alpha;
      }
      mrun = mnew;
    }

    float ps = 0.f;
    unsigned short pb[8];
#pragma unroll
    for (int i = 0; i < 8; ++i) {
      float p = __expf(sv[i] - mrun);
      ps += p;
      pb[i] = f2bf(p);
    }
    ps += __shfl_xor(ps, 16);
    ps += __shfl_xor(ps, 32);
    lsum += ps;

    // P^T to per-wave LDS: P[q][kp], kp = frag*16 + g*4 + rr
    unsigned* pw0 = (unsigned*)&P[w][lq * 40 + g * 4];
    pw0[0] = (unsigned)pb[0] | ((unsigned)pb[1] << 16);
    pw0[1] = (unsigned)pb[2] | ((unsigned)pb[3] << 16);
    unsigned* pw1 = (unsigned*)&P[w][lq * 40 + 16 + g * 4];
    pw1[0] = (unsigned)pb[4] | ((unsigned)pb[5] << 16);
    pw1[1] = (unsigned)pb[6] | ((unsigned)pb[7] << 16);

    short8 pf = *(const short8*)&P[w][lq * 40 + g * 8];
    __builtin_amdgcn_s_setprio(1);
#pragma unroll
    for (int dt = 0; dt < 16; ++dt)
      acc[dt] = __builtin_amdgcn_mfma_f32_16x16x32_bf16(vf[dt], pf, acc[dt], 0, 0, 0);
    __builtin_amdgcn_s_setprio(0);

    __syncthreads();   // drains stage loads (vmcnt) + swaps buffers
  }

  float inv = 1.0f / lsum;
  size_t obase = ((size_t)(b * SEQ + q)) * DMODEL + h * HD;
#pragma unroll
  for (int dt = 0; dt < 16; ++dt) {
    unsigned short o0 = f2bf(acc[dt][0] * inv);
    unsigned short o1 = f2bf(acc[dt][1] * inv);
    unsigned short o2 = f2bf(acc[dt][2] * inv);
    unsigned short o3 = f2bf(acc[dt][3] * inv);
    uint2 pk;
    pk.x = (unsigned)o0 | ((unsigned)o1 << 16);
    pk.y = (unsigned)o2 | ((unsigned)o3 << 16);
    *(uint2*)&ao[obase + dt * 16 + g * 4] = pk;
  }
}

// ---------------- out projection + bias + residual -> y (fp32) ----------------
__global__ __launch_bounds__(256) void gemm_out_kernel(
    const unsigned short* __restrict__ A,    // attn_out [8192][1024]
    const unsigned short* __restrict__ Bt,   // woutT    [1024][1024]
    const float* __restrict__ bias,          // [1024]
    const float* __restrict__ x,             // [8192][1024] fp32
    float* __restrict__ y) {                 // [8192][1024] fp32
  __shared__ __align__(16) unsigned short sA[128 * 32];
  __shared__ __align__(16) unsigned short sB[128 * 32];
  const int t = threadIdx.x;
  const int l = t & 63, w = t >> 6;
  const int g = l >> 4, lr = l & 15;
  const int wr = w >> 1, wc = w & 1;
  const int row0 = blockIdx.y * 128;
  const int col0 = blockIdx.x * 128;

  f32x4 acc[4][4] = {};
  for (int kt = 0; kt < 1024; kt += 32) {
    __syncthreads();
#pragma unroll
    for (int i = 0; i < 2; ++i) {
      int e = i * 256 + t;
      async16(&sA[e * 8], A + (size_t)(row0 + (e >> 2)) * 1024 + kt + (e & 3) * 8);
      async16(&sB[e * 8], Bt + (size_t)(col0 + (e >> 2)) * 1024 + kt + (e & 3) * 8);
    }
    __syncthreads();
    short8 af[4], bf[4];
#pragma unroll
    for (int m = 0; m < 4; ++m)
      af[m] = *(const short8*)&sA[(wr * 64 + m * 16 + lr) * 32 + g * 8];
#pragma unroll
    for (int n = 0; n < 4; ++n)
      bf[n] = *(const short8*)&sB[(wc * 64 + n * 16 + lr) * 32 + g * 8];
#pragma unroll
    for (int m = 0; m < 4; ++m)
#pragma unroll
      for (int n = 0; n < 4; ++n)
        acc[m][n] = __builtin_amdgcn_mfma_f32_16x16x32_bf16(af[m], bf[n], acc[m][n], 0, 0, 0);
  }

#pragma unroll
  for (int m = 0; m < 4; ++m) {
    int rowb = row0 + wr * 64 + m * 16 + g * 4;
#pragma unroll
    for (int nn = 0; nn < 4; ++nn) {
      int col = col0 + wc * 64 + nn * 16 + lr;
      float bv = bias[col];
#pragma unroll
      for (int rr = 0; rr < 4; ++rr) {
        size_t idx = (size_t)(rowb + rr) * 1024 + col;
        y[idx] = acc[m][nn][rr] + bv + x[idx];
      }
    }
  }
}

// ---------------- LayerNorm over last dim (1024) ----------------
__global__ __launch_bounds__(256) void ln_kernel(
    const float* __restrict__ y, const float* __restrict__ gamma,
    const float* __restrict__ beta, float* __restrict__ out) {
  int row = blockIdx.x, t = threadIdx.x;
  float4 v = ((const float4*)(y + (size_t)row * 1024))[t];
  float s = v.x + v.y + v.z + v.w;
  float qs = v.x * v.x + v.y * v.y + v.z * v.z + v.w * v.w;
#pragma unroll
  for (int off = 1; off < 64; off <<= 1) {
    s += __shfl_xor(s, off);
    qs += __shfl_xor(qs, off);
  }
  __shared__ float ss[4], qq[4];
  if ((t & 63) == 0) { ss[t >> 6] = s; qq[t >> 6] = qs; }
  __syncthreads();
  s = ss[0] + ss[1] + ss[2] + ss[3];
  qs = qq[0] + qq[1] + qq[2] + qq[3];
  float mean = s * (1.0f / 1024.0f);
  float var = qs * (1.0f / 1024.0f) - mean * mean;
  float rstd = rsqrtf(var + 1e-5f);
  float4 gm = ((const float4*)gamma)[t];
  float4 bt = ((const float4*)beta)[t];
  float4 o;
  o.x = (v.x - mean) * rstd * gm.x + bt.x;
  o.y = (v.y - mean) * rstd * gm.y + bt.y;
  o.z = (v.z - mean) * rstd * gm.z + bt.z;
  o.w = (v.w - mean) * rstd * gm.w + bt.w;
  ((float4*)(out + (size_t)row * 1024))[t] = o;
}

// ---------------- launch ----------------
extern "C" void kernel_launch(void* const* d_in, const int* in_sizes, int n_in,
                              void* d_out, int out_size, void* d_ws, size_t ws_size,
                              hipStream_t stream) {
  const float* x      = (const float*)d_in[0];
  const float* w_qkv  = (const float*)d_in[1];
  const float* b_qkv  = (const float*)d_in[2];
  const float* w_out  = (const float*)d_in[3];
  const float* b_out  = (const float*)d_in[4];
  const float* gamma  = (const float*)d_in[5];
  const float* beta   = (const float*)d_in[6];
  float* out = (float*)d_out;

  char* ws = (char*)d_ws;
  unsigned short* xb    = (unsigned short*)(ws);                 // 16 MB
  unsigned short* wqkvT = (unsigned short*)(ws + (16u << 20));   //  6 MB
  unsigned short* woutT = (unsigned short*)(ws + (22u << 20));   //  2 MB
  unsigned short* qb    = (unsigned short*)(ws + (24u << 20));   // 16 MB
  unsigned short* kb    = (unsigned short*)(ws + (40u << 20));   // 16 MB
  unsigned short* vt    = (unsigned short*)(ws + (56u << 20));   // 16 MB
  unsigned short* ao    = (unsigned short*)(ws + (72u << 20));   // 16 MB
  float* y              = (float*)(ws + (88u << 20));            // 32 MB

  cast_bf16_kernel<<<(BATCH * SEQ * DMODEL) / (256 * 4), 256, 0, stream>>>(x, xb);
  transpose_cast_kernel<<<dim3(96, 32), dim3(32, 8), 0, stream>>>(w_qkv, wqkvT, 1024, 3072);
  transpose_cast_kernel<<<dim3(32, 32), dim3(32, 8), 0, stream>>>(w_out, woutT, 1024, 1024);
  gemm_qkv_kernel<<<dim3(24, 64), 256, 0, stream>>>(xb, wqkvT, b_qkv, qb, kb, vt);
  attn_kernel<<<512, 256, 0, stream>>>(qb, kb, vt, ao);
  gemm_out_kernel<<<dim3(8, 64), 256, 0, stream>>>(ao, woutT, b_out, x, y);
  ln_kernel<<<BATCH * SEQ, 256, 0, stream>>>(y, gamma, beta, out);
}

// Round 3
// 249.252 us; speedup vs baseline: 2.4040x; 1.6558x over previous
//
#include <hip/hip_runtime.h>
#include <hip/hip_bf16.h>

// ---------------- types & helpers ----------------
typedef __attribute__((ext_vector_type(8))) short short8;   // 8 bf16 (4 VGPR)
typedef __attribute__((ext_vector_type(4))) float f32x4;    // MFMA C/D frag

#define GLOB_AS __attribute__((address_space(1)))
#define LDS_AS  __attribute__((address_space(3)))

__device__ __forceinline__ void async16(void* lds, const void* g) {
  __builtin_amdgcn_global_load_lds((const GLOB_AS unsigned int*)g,
                                   (LDS_AS unsigned int*)lds, 16, 0, 0);
}

__device__ __forceinline__ unsigned short f2bf(float f) {
  unsigned u = __float_as_uint(f);
  unsigned r = u + 0x7FFFu + ((u >> 16) & 1u);   // RNE
  return (unsigned short)(r >> 16);
}

// dims
#define BATCH 4
#define SEQ   2048
#define DMODEL 1024
#define NHEAD 4
#define HD    256

// ---------------- cast x -> bf16 ----------------
__global__ __launch_bounds__(256) void cast_bf16_kernel(
    const float* __restrict__ in, unsigned short* __restrict__ out) {
  int i = blockIdx.x * 256 + threadIdx.x;   // handles 4 elements
  float4 v = ((const float4*)in)[i];
  uint2 o;
  o.x = (unsigned)f2bf(v.x) | ((unsigned)f2bf(v.y) << 16);
  o.y = (unsigned)f2bf(v.z) | ((unsigned)f2bf(v.w) << 16);
  ((uint2*)out)[i] = o;
}

// ---------------- transpose + cast weights: out[c][r] = bf16(in[r][c]) ----------------
__global__ __launch_bounds__(256) void transpose_cast_kernel(
    const float* __restrict__ in, unsigned short* __restrict__ out, int R, int C) {
  __shared__ float tile[32][33];
  int c0 = blockIdx.x * 32, r0 = blockIdx.y * 32;
  int tx = threadIdx.x, ty = threadIdx.y;  // (32, 8)
#pragma unroll
  for (int i = 0; i < 4; ++i)
    tile[ty + 8 * i][tx] = in[(size_t)(r0 + ty + 8 * i) * C + c0 + tx];
  __syncthreads();
#pragma unroll
  for (int i = 0; i < 4; ++i)
    out[(size_t)(c0 + ty + 8 * i) * R + r0 + tx] = f2bf(tile[tx][ty + 8 * i]);
}

// ---------------- QKV GEMM: C[8192,3072] = xb * wqkvT^T + b ----------------
__global__ __launch_bounds__(256) void gemm_qkv_kernel(
    const unsigned short* __restrict__ A,    // xb   [8192][1024]
    const unsigned short* __restrict__ Bt,   // wqkvT[3072][1024]
    const float* __restrict__ bias,          // [3072]
    unsigned short* __restrict__ qb,         // [16][2048][256]
    unsigned short* __restrict__ kb,         // [16][2048][256]
    unsigned short* __restrict__ vt) {       // [16][256][2048]
  __shared__ __align__(16) unsigned short sA[128 * 32];
  __shared__ __align__(16) unsigned short sB[128 * 32];
  const int t = threadIdx.x;
  const int l = t & 63, w = t >> 6;
  const int g = l >> 4, lr = l & 15;
  const int wr = w >> 1, wc = w & 1;
  const int row0 = blockIdx.y * 128;
  const int col0 = blockIdx.x * 128;

  f32x4 acc[4][4] = {};
  for (int kt = 0; kt < 1024; kt += 32) {
    __syncthreads();
#pragma unroll
    for (int i = 0; i < 2; ++i) {
      int e = i * 256 + t;
      async16(&sA[e * 8], A + (size_t)(row0 + (e >> 2)) * 1024 + kt + (e & 3) * 8);
      async16(&sB[e * 8], Bt + (size_t)(col0 + (e >> 2)) * 1024 + kt + (e & 3) * 8);
    }
    __syncthreads();
    short8 af[4], bf[4];
#pragma unroll
    for (int m = 0; m < 4; ++m)
      af[m] = *(const short8*)&sA[(wr * 64 + m * 16 + lr) * 32 + g * 8];
#pragma unroll
    for (int n = 0; n < 4; ++n)
      bf[n] = *(const short8*)&sB[(wc * 64 + n * 16 + lr) * 32 + g * 8];
#pragma unroll
    for (int m = 0; m < 4; ++m)
#pragma unroll
      for (int n = 0; n < 4; ++n)
        acc[m][n] = __builtin_amdgcn_mfma_f32_16x16x32_bf16(af[m], bf[n], acc[m][n], 0, 0, 0);
  }

  // epilogue: C layout col=lane&15, row=(lane>>4)*4+reg
#pragma unroll
  for (int m = 0; m < 4; ++m) {
    int rowb = row0 + wr * 64 + m * 16 + g * 4;  // + rr
    int b = rowb >> 11;
    int nb = rowb & 2047;
#pragma unroll
    for (int nn = 0; nn < 4; ++nn) {
      int col = col0 + wc * 64 + nn * 16 + lr;
      float bv = bias[col];
      int sec = col >> 10, c1 = col & 1023;
      int h = c1 >> 8, d = c1 & 255;
      if (sec == 2) {  // V -> transposed [bh][d][n], pack 4 consecutive n
        unsigned short p0 = f2bf(acc[m][nn][0] + bv);
        unsigned short p1 = f2bf(acc[m][nn][1] + bv);
        unsigned short p2 = f2bf(acc[m][nn][2] + bv);
        unsigned short p3 = f2bf(acc[m][nn][3] + bv);
        uint2 pk;
        pk.x = (unsigned)p0 | ((unsigned)p1 << 16);
        pk.y = (unsigned)p2 | ((unsigned)p3 << 16);
        size_t idx = ((size_t)((b * NHEAD + h) * HD + d)) * SEQ + nb;
        *(uint2*)&vt[idx] = pk;
      } else {
        unsigned short* dst = (sec == 0) ? qb : kb;
#pragma unroll
        for (int rr = 0; rr < 4; ++rr) {
          size_t idx = ((size_t)((b * NHEAD + h) * SEQ + nb + rr)) * HD + d;
          dst[idx] = f2bf(acc[m][nn][rr] + bv);
        }
      }
    }
  }
}

// ---------------- attention ----------------
// Per-wave 16 q rows, swapped orientation:
//   S^T[kp][q]   = sum_d K[kp][d] Q[q][d]        (A = K frag from LDS, B = Q frag)
//   acc^T[d][q] += sum_kp V^T[d][kp] P^T[kp][q]  (A = V^T frag from LDS, B = P frag)
// K chunk [32][256] (XOR-swizzled rows, stride 512B) and V^T chunk [256][32]
// (linear, 64B rows) both double-buffered in LDS via global_load_lds.
// XCD swizzle: blocks of the same head pinned to one XCD for L2 residency.
__global__ __launch_bounds__(256, 2) void attn_kernel(
    const unsigned short* __restrict__ qb,
    const unsigned short* __restrict__ kb,
    const unsigned short* __restrict__ vt,
    unsigned short* __restrict__ ao) {       // [8192][1024] bf16
  __shared__ __align__(16) unsigned short sK[2][32 * 256];   // 16 KB per buffer
  __shared__ __align__(16) unsigned short sV[2][256 * 32];   // 16 KB per buffer
  __shared__ __align__(16) unsigned short P[4][16 * 40];     // per-wave, stride 40
  const int t = threadIdx.x, l = t & 63, w = t >> 6;
  const int g = l >> 4, lq = l & 15;
  // XCD-aware decode: bid%8 == XCD; XCD x owns heads {2x, 2x+1}
  const int bid = blockIdx.x;
  const int bh = (bid & 7) * 2 + ((bid >> 3) & 1);
  const int qblk = bid >> 4;
  const int b = bh >> 2, h = bh & 3;
  const int q = qblk * 64 + w * 16 + lq;
  const unsigned short* Qp = qb + (size_t)bh * SEQ * HD;
  const char* Kg = (const char*)(kb + (size_t)bh * SEQ * HD);
  const char* Vg = (const char*)(vt + (size_t)bh * HD * SEQ);

  short8 qf[8];
#pragma unroll
  for (int dc = 0; dc < 8; ++dc)
    qf[dc] = *(const short8*)&Qp[(size_t)q * HD + dc * 32 + g * 8];

  // stage K chunk [kp0..kp0+32)x[256] into sK[buf]: linear dest, inverse-swizzled src
  // stage V^T chunk [256]x[kp0..kp0+32) into sV[buf]: linear dest+src (64B rows)
  auto stage = [&](int buf, int kp0) {
#pragma unroll
    for (int i = 0; i < 4; ++i) {
      int s = w * 256 + i * 64 + l;            // 16B slot index, 0..1023
      int row = s >> 5;                         // 0..31
      int colb = (s & 31) * 16;                 // byte col in row
      int src = (kp0 + row) * 512 + (colb ^ ((row & 7) << 4));
      async16((char*)sK[buf] + s * 16, Kg + src);
    }
#pragma unroll
    for (int i = 0; i < 4; ++i) {
      int s = w * 256 + i * 64 + l;            // 16B slot, 0..1023
      int row = s >> 2;                         // 0..255 (d index)
      int colb = (s & 3) * 16;                  // 0..48, within 64B row
      async16((char*)sV[buf] + s * 16, Vg + row * (SEQ * 2) + kp0 * 2 + colb);
    }
  };

  stage(0, 0);
  __syncthreads();

  f32x4 acc[16] = {};
  float mrun = -__builtin_inff();
  float lsum = 0.f;
  const float scale = 0.0625f;  // 1/sqrt(256)

  for (int it = 0; it < 64; ++it) {
    const int kp0 = it * 32;
    const int cur = it & 1;
    if (it < 63) stage(cur ^ 1, kp0 + 32);   // prefetch next chunk (async)

    // QK^T from swizzled LDS K
    f32x4 s0 = {}, s1 = {};
    __builtin_amdgcn_s_setprio(1);
#pragma unroll
    for (int dc = 0; dc < 8; ++dc) {
      int c = dc * 64 + g * 16;
      short8 k0 = *(const short8*)((const char*)sK[cur] +
                    (lq * 512 + (c ^ ((lq & 7) << 4))));
      short8 k1 = *(const short8*)((const char*)sK[cur] +
                    ((lq + 16) * 512 + (c ^ ((lq & 7) << 4))));
      s0 = __builtin_amdgcn_mfma_f32_16x16x32_bf16(k0, qf[dc], s0, 0, 0, 0);
      s1 = __builtin_amdgcn_mfma_f32_16x16x32_bf16(k1, qf[dc], s1, 0, 0, 0);
    }
    __builtin_amdgcn_s_setprio(0);

    float sv[8];
#pragma unroll
    for (int i = 0; i < 4; ++i) { sv[i] = s0[i] * scale; sv[4 + i] = s1[i] * scale; }
    float cmax = sv[0];
#pragma unroll
    for (int i = 1; i < 8; ++i) cmax = fmaxf(cmax, sv[i]);
    cmax = fmaxf(cmax, __shfl_xor(cmax, 16));
    cmax = fmaxf(cmax, __shfl_xor(cmax, 32));

    // defer-max: only rescale when running max moved by > 8
    if (!__all(cmax <= mrun + 8.0f)) {
      float mnew = fmaxf(mrun, cmax);
      float alpha = __expf(mrun - mnew);
      lsum *= alpha;
#pragma unroll
      for (int dt = 0; dt < 16; ++dt) {
#pragma unroll
        for (int rr = 0; rr < 4; ++rr) acc[dt][rr] *= alpha;
      }
      mrun = mnew;
    }

    float ps = 0.f;
    unsigned short pb[8];
#pragma unroll
    for (int i = 0; i < 8; ++i) {
      float p = __expf(sv[i] - mrun);
      ps += p;
      pb[i] = f2bf(p);
    }
    ps += __shfl_xor(ps, 16);
    ps += __shfl_xor(ps, 32);
    lsum += ps;

    // P^T to per-wave LDS: P[q][kp], kp = frag*16 + g*4 + rr
    unsigned* pw0 = (unsigned*)&P[w][lq * 40 + g * 4];
    pw0[0] = (unsigned)pb[0] | ((unsigned)pb[1] << 16);
    pw0[1] = (unsigned)pb[2] | ((unsigned)pb[3] << 16);
    unsigned* pw1 = (unsigned*)&P[w][lq * 40 + 16 + g * 4];
    pw1[0] = (unsigned)pb[4] | ((unsigned)pb[5] << 16);
    pw1[1] = (unsigned)pb[6] | ((unsigned)pb[7] << 16);

    short8 pf = *(const short8*)&P[w][lq * 40 + g * 8];

    // PV: V^T frags from LDS [d=dt*16+lq][kp=g*8..+8]
    __builtin_amdgcn_s_setprio(1);
#pragma unroll
    for (int dt = 0; dt < 16; ++dt) {
      short8 vf = *(const short8*)((const char*)sV[cur] +
                    ((dt * 16 + lq) * 64 + g * 16));
      acc[dt] = __builtin_amdgcn_mfma_f32_16x16x32_bf16(vf, pf, acc[dt], 0, 0, 0);
    }
    __builtin_amdgcn_s_setprio(0);

    __syncthreads();   // drains stage loads (vmcnt) + swaps buffers
  }

  float inv = 1.0f / lsum;
  size_t obase = ((size_t)(b * SEQ + q)) * DMODEL + h * HD;
#pragma unroll
  for (int dt = 0; dt < 16; ++dt) {
    unsigned short o0 = f2bf(acc[dt][0] * inv);
    unsigned short o1 = f2bf(acc[dt][1] * inv);
    unsigned short o2 = f2bf(acc[dt][2] * inv);
    unsigned short o3 = f2bf(acc[dt][3] * inv);
    uint2 pk;
    pk.x = (unsigned)o0 | ((unsigned)o1 << 16);
    pk.y = (unsigned)o2 | ((unsigned)o3 << 16);
    *(uint2*)&ao[obase + dt * 16 + g * 4] = pk;
  }
}

// ---------------- out projection + bias + residual -> y (fp32) ----------------
__global__ __launch_bounds__(256) void gemm_out_kernel(
    const unsigned short* __restrict__ A,    // attn_out [8192][1024]
    const unsigned short* __restrict__ Bt,   // woutT    [1024][1024]
    const float* __restrict__ bias,          // [1024]
    const float* __restrict__ x,             // [8192][1024] fp32
    float* __restrict__ y) {                 // [8192][1024] fp32
  __shared__ __align__(16) unsigned short sA[128 * 32];
  __shared__ __align__(16) unsigned short sB[128 * 32];
  const int t = threadIdx.x;
  const int l = t & 63, w = t >> 6;
  const int g = l >> 4, lr = l & 15;
  const int wr = w >> 1, wc = w & 1;
  const int row0 = blockIdx.y * 128;
  const int col0 = blockIdx.x * 128;

  f32x4 acc[4][4] = {};
  for (int kt = 0; kt < 1024; kt += 32) {
    __syncthreads();
#pragma unroll
    for (int i = 0; i < 2; ++i) {
      int e = i * 256 + t;
      async16(&sA[e * 8], A + (size_t)(row0 + (e >> 2)) * 1024 + kt + (e & 3) * 8);
      async16(&sB[e * 8], Bt + (size_t)(col0 + (e >> 2)) * 1024 + kt + (e & 3) * 8);
    }
    __syncthreads();
    short8 af[4], bf[4];
#pragma unroll
    for (int m = 0; m < 4; ++m)
      af[m] = *(const short8*)&sA[(wr * 64 + m * 16 + lr) * 32 + g * 8];
#pragma unroll
    for (int n = 0; n < 4; ++n)
      bf[n] = *(const short8*)&sB[(wc * 64 + n * 16 + lr) * 32 + g * 8];
#pragma unroll
    for (int m = 0; m < 4; ++m)
#pragma unroll
      for (int n = 0; n < 4; ++n)
        acc[m][n] = __builtin_amdgcn_mfma_f32_16x16x32_bf16(af[m], bf[n], acc[m][n], 0, 0, 0);
  }

#pragma unroll
  for (int m = 0; m < 4; ++m) {
    int rowb = row0 + wr * 64 + m * 16 + g * 4;
#pragma unroll
    for (int nn = 0; nn < 4; ++nn) {
      int col = col0 + wc * 64 + nn * 16 + lr;
      float bv = bias[col];
#pragma unroll
      for (int rr = 0; rr < 4; ++rr) {
        size_t idx = (size_t)(rowb + rr) * 1024 + col;
        y[idx] = acc[m][nn][rr] + bv + x[idx];
      }
    }
  }
}

// ---------------- LayerNorm over last dim (1024) ----------------
__global__ __launch_bounds__(256) void ln_kernel(
    const float* __restrict__ y, const float* __restrict__ gamma,
    const float* __restrict__ beta, float* __restrict__ out) {
  int row = blockIdx.x, t = threadIdx.x;
  float4 v = ((const float4*)(y + (size_t)row * 1024))[t];
  float s = v.x + v.y + v.z + v.w;
  float qs = v.x * v.x + v.y * v.y + v.z * v.z + v.w * v.w;
#pragma unroll
  for (int off = 1; off < 64; off <<= 1) {
    s += __shfl_xor(s, off);
    qs += __shfl_xor(qs, off);
  }
  __shared__ float ss[4], qq[4];
  if ((t & 63) == 0) { ss[t >> 6] = s; qq[t >> 6] = qs; }
  __syncthreads();
  s = ss[0] + ss[1] + ss[2] + ss[3];
  qs = qq[0] + qq[1] + qq[2] + qq[3];
  float mean = s * (1.0f / 1024.0f);
  float var = qs * (1.0f / 1024.0f) - mean * mean;
  float rstd = rsqrtf(var + 1e-5f);
  float4 gm = ((const float4*)gamma)[t];
  float4 bt = ((const float4*)beta)[t];
  float4 o;
  o.x = (v.x - mean) * rstd * gm.x + bt.x;
  o.y = (v.y - mean) * rstd * gm.y + bt.y;
  o.z = (v.z - mean) * rstd * gm.z + bt.z;
  o.w = (v.w - mean) * rstd * gm.w + bt.w;
  ((float4*)(out + (size_t)row * 1024))[t] = o;
}

// ---------------- launch ----------------
extern "C" void kernel_launch(void* const* d_in, const int* in_sizes, int n_in,
                              void* d_out, int out_size, void* d_ws, size_t ws_size,
                              hipStream_t stream) {
  const float* x      = (const float*)d_in[0];
  const float* w_qkv  = (const float*)d_in[1];
  const float* b_qkv  = (const float*)d_in[2];
  const float* w_out  = (const float*)d_in[3];
  const float* b_out  = (const float*)d_in[4];
  const float* gamma  = (const float*)d_in[5];
  const float* beta   = (const float*)d_in[6];
  float* out = (float*)d_out;

  char* ws = (char*)d_ws;
  unsigned short* xb    = (unsigned short*)(ws);                 // 16 MB
  unsigned short* wqkvT = (unsigned short*)(ws + (16u << 20));   //  6 MB
  unsigned short* woutT = (unsigned short*)(ws + (22u << 20));   //  2 MB
  unsigned short* qb    = (unsigned short*)(ws + (24u << 20));   // 16 MB
  unsigned short* kb    = (unsigned short*)(ws + (40u << 20));   // 16 MB
  unsigned short* vt    = (unsigned short*)(ws + (56u << 20));   // 16 MB
  unsigned short* ao    = (unsigned short*)(ws + (72u << 20));   // 16 MB
  float* y              = (float*)(ws + (88u << 20));            // 32 MB

  cast_bf16_kernel<<<(BATCH * SEQ * DMODEL) / (256 * 4), 256, 0, stream>>>(x, xb);
  transpose_cast_kernel<<<dim3(96, 32), dim3(32, 8), 0, stream>>>(w_qkv, wqkvT, 1024, 3072);
  transpose_cast_kernel<<<dim3(32, 32), dim3(32, 8), 0, stream>>>(w_out, woutT, 1024, 1024);
  gemm_qkv_kernel<<<dim3(24, 64), 256, 0, stream>>>(xb, wqkvT, b_qkv, qb, kb, vt);
  attn_kernel<<<512, 256, 0, stream>>>(qb, kb, vt, ao);
  gemm_out_kernel<<<dim3(8, 64), 256, 0, stream>>>(ao, woutT, b_out, x, y);
  ln_kernel<<<BATCH * SEQ, 256, 0, stream>>>(y, gamma, beta, out);
}